// Round 12
// baseline (185.259 us; speedup 1.0000x reference)
//
#include <hip/hip_runtime.h>
#include <stdint.h>

typedef unsigned short u16;
typedef __attribute__((ext_vector_type(8))) __bf16 bf16x8;
typedef __attribute__((ext_vector_type(4))) float f32x4;
typedef __attribute__((ext_vector_type(4))) u16 u16x4;
typedef __attribute__((ext_vector_type(8))) u16 u16x8;

#define N_IMG 64
#define C_IN  64
#define HW_IN 3136   // 56*56
#define W_IN  56
#define C_OUT 128
#define OH    54
#define OW    54
#define SPI   2916   // 54*54 (div by 4 -> dwordx4 tail mask exact)
#define KTOT  576    // C_IN*9
#define SP_BLK 128
#define NBPI  23     // ceil(SPI/128)
#define NWG   (N_IMG*NBPI)   // 1472 = 8*184
#define SLAB_ROWS 256

typedef __attribute__((address_space(3))) unsigned int lds_uint;
typedef __attribute__((address_space(1))) unsigned int gbl_uint;

__device__ __forceinline__ void load16_to_lds(const u16* g, u16* l) {
  __builtin_amdgcn_global_load_lds((const gbl_uint*)g, (lds_uint*)l, 16, 0, 0);
}

__device__ inline u16 f32_bf16_rne(float f) {
  unsigned u = __float_as_uint(f);
  u = (u + 0x7FFFu + ((u >> 16) & 1u)) >> 16;
  return (u16)u;
}

__device__ __forceinline__ bf16x8 as_bf16x8(f32x4 v) {
  union { f32x4 f; bf16x8 b; } u; u.f = v; return u.b;
}

// pinned (volatile) 16B global load: compiler cannot sink/rematerialize it
// (the r5/r6 failure mode). Early-clobber "=&v": dst quad never aliases the
// address pair. Completion is claimed ONLY by our counted vmcnt.
#define GLOAD16(dst, ptr) \
  asm volatile("global_load_dwordx4 %0, %1, off" \
               : "=&v"(dst) : "v"(ptr) : "memory")
#define WAITV(n) asm volatile("s_waitcnt vmcnt(" #n ")" ::: "memory")

// Merged converter (unchanged).
__global__ __launch_bounds__(256) void convert_xw(
    const float* __restrict__ x, const float* __restrict__ w,
    u16* __restrict__ xt, u16* __restrict__ wtT)
{
  if (blockIdx.y == N_IMG) {
    int o = blockIdx.x * 256 + threadIdx.x;
    for (; o < C_OUT * KTOT; o += 49 * 256) {
      int co = o / KTOT;
      int k  = o - co * KTOT;
      int t  = k >> 6;
      int ci = k & 63;
      wtT[o] = f32_bf16_rne(w[co * KTOT + ci * 9 + t]);
    }
    return;
  }

  __shared__ u16 tile[64][68];
  int n  = blockIdx.y;
  int s0 = blockIdx.x * 64;
  int t  = threadIdx.x;

  int r = t >> 2;
  int q = t & 3;
  const float* xp = x + (size_t)n * C_IN * HW_IN + (size_t)r * HW_IN + s0 + q * 16;
  #pragma unroll
  for (int j = 0; j < 4; j++) {
    f32x4 v = *(const f32x4*)(xp + 4 * j);
    u16x4 o4;
    #pragma unroll
    for (int e = 0; e < 4; e++) {
      float f = fminf(fmaxf(v[e], -128.f), 127.f);
      int iv = (int)f;
      o4[e] = f32_bf16_rne((float)iv);
    }
    *(u16x4*)&tile[r][q * 16 + 4 * j] = o4;
  }
  __syncthreads();

  u16* op = xt + ((size_t)n * HW_IN + s0) * C_IN;
  int g = t & 7;
  int m = t >> 3;
  #pragma unroll
  for (int k2 = 0; k2 < 2; k2++) {
    int sp = m * 2 + k2;
    u16x8 o8;
    #pragma unroll
    for (int c = 0; c < 8; c++) o8[c] = tile[g * 8 + c][sp];
    *(u16x8*)&op[(size_t)sp * C_IN + g * 8] = o8;
  }
}

// Implicit GEMM v11b: W-IN-REGISTERS, barrier-free decoupled K-loop.
// Pixels: 32 KB halo slab staged once (global_load_lds), ONE prologue barrier.
// Weights: each lane volatile-loads its own MFMA A-fragments 2 taps ahead into
//   a 3-slot register ring (f32x4 w[3][4][2], 96 VGPR). Counted vmcnt(16)
//   retires exactly tap-kc's 8 loads (in flight ~2 full taps -> latency
//   hidden); never drains in-loop. sched_barrier(0) after each wait stops
//   MFMAs hoisting above it (rule #18). Safe-by-age: compiler-hoisted loads
//   are OLDER so counted waits still cover the target tap; bias is loaded
//   only after the final vmcnt(0).
// Result: zero barriers, zero LDS-W traffic in the loop (8 pf ds_reads/tap),
//   waves fully independent -> per-wave pipelining + setprio arbitration.
__global__ __launch_bounds__(256, 2) void conv_gemm(
    const u16* __restrict__ xt, const u16* __restrict__ wtT,
    const float* __restrict__ bias, float* __restrict__ y)
{
  __shared__ u16 smem[32768];           // 64 KB: [0,32K)=slab; epilogue patch overlays
  u16* slab = smem;

  int tid  = threadIdx.x;
  int wv   = tid >> 6;           // 0..3
  int lane = tid & 63;
  int ln   = lane & 15;
  int q    = lane >> 4;
  int wy   = wv >> 1;            // cout half (64 rows)
  int wx   = wv & 1;             // spatial half (64 cols)

  // XCD-aware swizzle: 1472 = 8*184
  int b  = blockIdx.x;
  int wg = (b & 7) * (NWG / 8) + (b >> 3);
  int img = wg / NBPI;
  int cb  = wg - img * NBPI;
  int r0  = cb * SP_BLK;
  int ibase = r0 + 2 * (r0 / OW);

  const u16* xti = xt + (size_t)img * HW_IN * C_IN;

  int trow = tid >> 3;
  int cg   = tid & 7;

  // ---- slab staging FIRST (8 DMAs = oldest vmcnt entries) ----
  #pragma unroll
  for (int j = 0; j < 8; j++) {
    int row  = j * 32 + trow;
    int grow = ibase + row;
    if (grow > HW_IN - 1) grow = HW_IN - 1;
    load16_to_lds(xti + (size_t)grow * 64 + ((cg ^ (row & 7)) * 8),
                  slab + (size_t)(j * 256 + wv * 64) * 8);
  }

  // ---- per-lane W fragment bases: co = wy*64 + mt*16 + ln, k-group q ----
  const u16* wb[4];
  #pragma unroll
  for (int mt = 0; mt < 4; mt++)
    wb[mt] = wtT + (size_t)(wy * 64 + mt * 16 + ln) * KTOT + q * 8;

  // W register ring; all indices compile-time after full unroll (rule #20)
  f32x4 w[3][4][2];
  #pragma unroll
  for (int mt = 0; mt < 4; mt++)
    #pragma unroll
    for (int si = 0; si < 2; si++) {
      GLOAD16(w[0][mt][si], wb[mt] + si * 32);        // tap 0
    }
  #pragma unroll
  for (int mt = 0; mt < 4; mt++)
    #pragma unroll
    for (int si = 0; si < 2; si++) {
      GLOAD16(w[1][mt][si], wb[mt] + 64 + si * 32);   // tap 1
    }

  f32x4 acc[4][4];
  #pragma unroll
  for (int mt = 0; mt < 4; mt++)
    #pragma unroll
    for (int nt = 0; nt < 4; nt++)
      acc[mt][nt] = (f32x4){0.f, 0.f, 0.f, 0.f};

  int prel[4], rbase[4];
  #pragma unroll
  for (int nt = 0; nt < 4; nt++) {
    int pr = r0 + wx * 64 + nt * 16 + ln;
    prel[nt]  = pr;
    rbase[nt] = pr + 2 * (pr / OW) - ibase;
  }

  // outstanding = 8 slab + 16 W; retire the slab, keep W taps 0,1 in flight.
  WAITV(16);
  __builtin_amdgcn_s_barrier();          // slab visible to all waves
  __builtin_amdgcn_sched_barrier(0);     // no ds_read hoists above this point

  #pragma unroll
  for (int kc = 0; kc < 9; kc++) {
    const int slot = kc % 3;
    const int kh = kc / 3, kw = kc - kh * 3;
    const int koff = kh * W_IN + kw;

    // prefetch tap kc+2 into ring slot (kc+2)%3 (its regs dead since kc-1)
    if (kc < 7) {
      const int ns = (kc + 2) % 3;
      #pragma unroll
      for (int mt = 0; mt < 4; mt++)
        #pragma unroll
        for (int si = 0; si < 2; si++) {
          GLOAD16(w[ns][mt][si], wb[mt] + (kc + 2) * 64 + si * 32);
        }
    }

    #pragma unroll
    for (int si = 0; si < 2; si++) {
      int gg = si * 4 + q;
      bf16x8 pf[4];
      #pragma unroll
      for (int nt = 0; nt < 4; nt++) {
        int rb = rbase[nt] + koff;
        pf[nt] = *(const bf16x8*)(slab + rb * 64 + ((gg ^ (rb & 7)) * 8));
      }

      if (si == 0) {       // retire exactly tap kc's 8 W loads before first use
        if (kc < 7)       { WAITV(16); }
        else if (kc == 7) { WAITV(8); }
        else              { WAITV(0); }
        __builtin_amdgcn_sched_barrier(0);   // MFMAs must not hoist above wait
      }

      __builtin_amdgcn_s_setprio(1);
      #pragma unroll
      for (int mt = 0; mt < 4; mt++)
        #pragma unroll
        for (int nt = 0; nt < 4; nt++)
          acc[mt][nt] = __builtin_amdgcn_mfma_f32_16x16x32_bf16(
              as_bf16x8(w[slot][mt][si]), pf[nt], acc[mt][nt], 0, 0, 0);
      __builtin_amdgcn_s_setprio(0);
    }
  }

  // bias only AFTER the final vmcnt(0): keeps loop vmcnt accounting exact
  float bs[4][4];
  #pragma unroll
  for (int mt = 0; mt < 4; mt++)
    #pragma unroll
    for (int r = 0; r < 4; r++)
      bs[mt][r] = bias[wy * 64 + mt * 16 + q * 4 + r];

  // ---- epilogue: per-wave LDS transpose -> dwordx4 full-line stores ----
  __syncthreads();   // all waves done reading slab before patches overwrite it

  float* patch = (float*)smem + (size_t)wv * 4096;   // 16 KB / wave

  #pragma unroll
  for (int mt = 0; mt < 4; mt++)
    #pragma unroll
    for (int nt = 0; nt < 4; nt++)
      #pragma unroll
      for (int r = 0; r < 4; r++)
        patch[(mt * 16 + q * 4 + r) * 64 + nt * 16 + ln] =
            acc[mt][nt][r] + bs[mt][r];

  int pr0 = (lane & 15) * 4;
  int cr  = lane >> 4;
  int prg0 = r0 + wx * 64 + pr0;
  size_t ybase = (size_t)img * C_OUT * SPI + prg0;
  #pragma unroll
  for (int i = 0; i < 16; i++) {
    int co_l = i * 4 + cr;
    f32x4 v = *(const f32x4*)(patch + co_l * 64 + pr0);
    if (prg0 < SPI)
      *(f32x4*)(y + ybase + (size_t)(wy * 64 + co_l) * SPI) = v;
  }
}

extern "C" void kernel_launch(void* const* d_in, const int* in_sizes, int n_in,
                              void* d_out, int out_size, void* d_ws, size_t ws_size,
                              hipStream_t stream) {
  const float* x    = (const float*)d_in[0];
  const float* w    = (const float*)d_in[1];
  const float* bias = (const float*)d_in[2];
  float* y = (float*)d_out;

  u16* wtT = (u16*)d_ws;
  u16* xt  = (u16*)((char*)d_ws + (size_t)C_OUT * KTOT * sizeof(u16)); // +147456 B

  hipLaunchKernelGGL(convert_xw, dim3(HW_IN / 64, N_IMG + 1), dim3(256), 0, stream,
                     x, w, xt, wtT);
  hipLaunchKernelGGL(conv_gemm, dim3(NWG), dim3(256), 0, stream,
                     xt, wtT, bias, y);
}